// Round 5
// baseline (649.709 us; speedup 1.0000x reference)
//
#include <hip/hip_runtime.h>
#include <hip/hip_bf16.h>
#include <cstdint>
#include <cstddef>

#define NROWS 32768
#define NCLS  1000
#define KP    1024   // padded class dim
#define NCH   32     // k-chunks per panel (KP/32)

typedef unsigned short u16;
typedef __bf16 bf16x8 __attribute__((ext_vector_type(8)));
typedef float  f32x4  __attribute__((ext_vector_type(4)));

// Fragment-chunk layout ("X4"): matrix [Rows][KP] stored as
//   chunk(R, c) = 1KB block at ((R*NCH)+c)*512 halfwords, R = row/16, c = k/32
//   slot l (l=0..63, 16B) = elements [R*16 + (l&15)][c*32 + (l>>4)*8 + j], j=0..7
// => a wave's MFMA A/B fragment (m=lane&15, k=(lane>>4)*8+j) is a CONTIGUOUS
//    coalesced 1KB global read at base+lane*16 — fragments load straight from
//    global to VGPR with no LDS and no layout transform.

// ---- prep: bank f32 [1000x1000] -> M4 and MT4 (fragment-chunk, zero-padded to 1024)
__global__ __launch_bounds__(128)
void prep4_bank(const float* __restrict__ bank,
                __hip_bfloat16* __restrict__ M4,
                __hip_bfloat16* __restrict__ MT4) {
  __shared__ float tile[32][33];
  const int tx = blockIdx.x;  // col chunk (k)
  const int ty = blockIdx.y;  // row chunk (j)
  const int t  = threadIdx.x;
  {
    const int r = t >> 2, c0 = (t & 3) * 8;
    const int gj = ty * 32 + r;
    #pragma unroll
    for (int j = 0; j < 8; ++j) {
      const int gk = tx * 32 + c0 + j;
      tile[r][c0 + j] = (gj < NCLS && gk < NCLS) ? bank[gj * NCLS + gk] : 0.0f;
    }
  }
  __syncthreads();
  const int w = t >> 6, lane = t & 63, lr = lane & 15, qq = lane >> 4;
  if (w == 0) {
    #pragma unroll
    for (int s = 0; s < 2; ++s) {
      bf16x8 o;
      #pragma unroll
      for (int j = 0; j < 8; ++j) o[j] = (__bf16)tile[s * 16 + lr][qq * 8 + j];
      *(bf16x8*)((u16*)M4 + ((size_t)(ty * 2 + s) * NCH + tx) * 512 + lane * 8) = o;
    }
  } else {
    #pragma unroll
    for (int s = 0; s < 2; ++s) {
      bf16x8 o;
      #pragma unroll
      for (int j = 0; j < 8; ++j) o[j] = (__bf16)tile[qq * 8 + j][s * 16 + lr];
      *(bf16x8*)((u16*)MT4 + ((size_t)(tx * 2 + s) * NCH + ty) * 512 + lane * 8) = o;
    }
  }
}

// ---- fused: p_tar -> A4 (fragment-chunk bf16), argmax agreement + segment-sum atomics
// One 16-row panel per BLOCK; the 4 waves k-split the 32 chunks (8 each)
// -> 2048 blocks x 4 waves for latency hiding. Partial argmax per wave combined
// through LDS; first-occurrence ties preserved (within-wave: index-min on equal;
// across waves: ascending k-range, strict >).
__global__ __launch_bounds__(256)
void rows4_kernel(const float* __restrict__ p_tar, const float* __restrict__ p_vlm,
                  __hip_bfloat16* __restrict__ A4,
                  float* __restrict__ sums, float* __restrict__ counts) {
  __shared__ float sT[4][16]; __shared__ int siT[4][16];
  __shared__ float sV[4][16]; __shared__ int siV[4][16];
  const int w = threadIdx.x >> 6, lane = threadIdx.x & 63;
  const int lr = lane & 15, q = lane >> 4;
  const int panel = blockIdx.x;                  // 0..2047
  const int row   = panel * 16 + lr;
  const float* tr = p_tar + (size_t)row * NCLS;
  const float* vr = p_vlm + (size_t)row * NCLS;
  u16* a4 = (u16*)A4 + (size_t)panel * NCH * 512 + lane * 8;

  float bvT = -1.0f; int biT = 0;
  float bvV = -1.0f; int biV = 0;
  for (int c = w * 8; c < w * 8 + 8; ++c) {
    const int k0 = c * 32 + q * 8;
    float v[8];
    if (k0 < NCLS) {
      float4 x = *(const float4*)(tr + k0);
      float4 y = *(const float4*)(tr + k0 + 4);
      v[0] = x.x; v[1] = x.y; v[2] = x.z; v[3] = x.w;
      v[4] = y.x; v[5] = y.y; v[6] = y.z; v[7] = y.w;
    } else {
      #pragma unroll
      for (int j = 0; j < 8; ++j) v[j] = 0.0f;
    }
    bf16x8 o;
    #pragma unroll
    for (int j = 0; j < 8; ++j) {
      o[j] = (__bf16)v[j];
      if (v[j] > bvT) { bvT = v[j]; biT = k0 + j; }
    }
    *(bf16x8*)(a4 + (size_t)c * 512) = o;
    if (k0 < NCLS) {
      float4 x = *(const float4*)(vr + k0);
      float4 y = *(const float4*)(vr + k0 + 4);
      float u[8] = {x.x, x.y, x.z, x.w, y.x, y.y, y.z, y.w};
      #pragma unroll
      for (int j = 0; j < 8; ++j)
        if (u[j] > bvV) { bvV = u[j]; biV = k0 + j; }
    }
  }
  // reduce across the 4 q-lanes owning row lr (xor 16, 32), first-occurrence ties
  #pragma unroll
  for (int d = 16; d < 64; d <<= 1) {
    float ov = __shfl_xor(bvT, d); int oi = __shfl_xor(biT, d);
    if (ov > bvT || (ov == bvT && oi < biT)) { bvT = ov; biT = oi; }
    float ov2 = __shfl_xor(bvV, d); int oi2 = __shfl_xor(biV, d);
    if (ov2 > bvV || (ov2 == bvV && oi2 < biV)) { bvV = ov2; biV = oi2; }
  }
  if (q == 0) { sT[w][lr] = bvT; siT[w][lr] = biT; sV[w][lr] = bvV; siV[w][lr] = biV; }
  __syncthreads();
  // combine k-quarters (all lanes: row lr), ascending w => strict > keeps min index
  float cT = sT[0][lr]; int ciT = siT[0][lr];
  float cV = sV[0][lr]; int ciV = siV[0][lr];
  #pragma unroll
  for (int ww = 1; ww < 4; ++ww) {
    float v1 = sT[ww][lr]; if (v1 > cT) { cT = v1; ciT = siT[ww][lr]; }
    float v2 = sV[ww][lr]; if (v2 > cV) { cV = v2; ciV = siV[ww][lr]; }
  }
  if (w == 0) {                                  // rare (~B/NCLS rows agree)
    const int ag = (ciT == ciV) ? 1 : 0;
    for (int rr = 0; rr < 16; ++rr) {
      const int agr = __shfl(ag, rr);
      if (agr) {                                 // wave-uniform
        const int cls = __shfl(ciT, rr);
        const float* trr = p_tar + (size_t)(panel * 16 + rr) * NCLS;
        for (int k = lane; k < NCLS; k += 64)
          atomicAdd(&sums[(size_t)cls * NCLS + k], trr[k]);
        if (lane == 0) atomicAdd(&counts[cls], 1.0f);
      }
    }
  }
}

// ---- fragment-chunk MFMA GEMM, BARRIER-FREE: no LDS staging at all.
// Both operands' fragments load DIRECTLY global->VGPR (contiguous 1KB per
// fragment in the X4 layout). A is L2-served (8 time-adjacent bn-sharers per
// XCD, round-3-verified FETCH ~= 1x A); B (2MB) is XCD-L2-resident. With no
// barriers and no vmcnt drains, waves pipeline independently and the compiler
// hoists next-iteration loads over MFMAs (unroll 2). Cost: 2x L2 traffic
// (no cross-wave operand sharing) ~ 2GB/gemm @ 34.5TB/s = 58us floor; gain:
// the ~400cyc/iter collective barrier+LDS round-trip disappears.
// LDS (32KB) is used ONLY by the WHICH==1 epilogue as a per-wave-private
// bounce (no sync needed).
// WHICH==1: E4 = frag-chunk bf16 exp(norm*S) (cols>=1000 -> 0) + atomic rowsum
// WHICH==2: p_mix row-major f32
template <int WHICH>
__global__ __launch_bounds__(256, 4)
void gemm4(const u16* __restrict__ A4, const u16* __restrict__ B4,
           __hip_bfloat16* __restrict__ E4out, float* __restrict__ rowsum,
           const float* __restrict__ p_vlm, float* __restrict__ mix_out) {
  __shared__ u16 SH[4][4096];   // epilogue bounce only (per-wave private 8KB)
  const int tid  = threadIdx.x;
  const int w    = tid >> 6;
  const int lane = tid & 63;
  const int lr   = lane & 15;
  const int q    = lane >> 4;
  const int L    = blockIdx.x;                    // 0..2047
  const int xcd  = L & 7;
  const int jj   = L >> 3;                        // 0..255 within-XCD dispatch order
  const int bm   = xcd * 32 + (jj >> 3);          // 0..255; 8 consecutive jj share bm
  const int bn   = jj & 7;                        // 0..7 fastest within XCD
  const int wm   = w >> 1;
  const int wn   = w & 1;

  f32x4 acc[4][4] = {};

  // each wave reads its own 4 A-panels (rows) and 4 B-panels (cols)
  const u16* ga[4];
  const u16* gb[4];
  #pragma unroll
  for (int t = 0; t < 4; ++t) {
    ga[t] = A4 + ((size_t)(bm * 8 + wm * 4 + t) * NCH) * 512 + lane * 8;
    gb[t] = B4 + ((size_t)(bn * 8 + wn * 4 + t) * NCH) * 512 + lane * 8;
  }

  #pragma unroll 2
  for (int i = 0; i < NCH; ++i) {
    const size_t kc = (size_t)i * 512;
    bf16x8 af[4], bfr[4];
    #pragma unroll
    for (int t = 0; t < 4; ++t) af[t]  = *(const bf16x8*)(ga[t] + kc);
    #pragma unroll
    for (int t = 0; t < 4; ++t) bfr[t] = *(const bf16x8*)(gb[t] + kc);
    #pragma unroll
    for (int mt = 0; mt < 4; ++mt)
      #pragma unroll
      for (int nt = 0; nt < 4; ++nt)
        acc[mt][nt] = __builtin_amdgcn_mfma_f32_16x16x32_bf16(af[mt], bfr[nt], acc[mt][nt], 0, 0, 0);
  }

  const float NORM = 0.03162277660168379f;  // 1/sqrt(1000)
  if (WHICH == 1) {
    u16* ep = &SH[w][0];             // 8KB per-wave private region, no sync needed
    #pragma unroll
    for (int mt = 0; mt < 4; ++mt) {
      float psum[4] = {0.f, 0.f, 0.f, 0.f};
      #pragma unroll
      for (int nt = 0; nt < 4; ++nt) {
        const int gn = bn * 128 + wn * 64 + nt * 16 + lr;
        const int cc = nt >> 1;                      // chunk within wave (0..1)
        const int q2 = (nt & 1) * 2 + (lr >> 3);     // k-subchunk in chunk
        const int jj2 = lr & 7;
        #pragma unroll
        for (int r = 0; r < 4; ++r) {
          float e = (gn < NCLS) ? __expf(acc[mt][nt][r] * NORM) : 0.0f;
          psum[r] += e;
          __hip_bfloat16 h = __float2bfloat16(e);
          ep[(mt * 2 + cc) * 512 + (q2 * 16 + q * 4 + r) * 8 + jj2] = *(u16*)&h;
        }
      }
      #pragma unroll
      for (int r = 0; r < 4; ++r) {
        float s = psum[r];
        s += __shfl_xor(s, 1); s += __shfl_xor(s, 2);
        s += __shfl_xor(s, 4); s += __shfl_xor(s, 8);
        if (lr == 0) atomicAdd(&rowsum[bm * 128 + wm * 64 + mt * 16 + q * 4 + r], s);
      }
    }
    #pragma unroll
    for (int ch = 0; ch < 8; ++ch) {   // coalesced 1KB flushes
      const int mt = ch >> 1, cc = ch & 1;
      bf16x8 v = *(const bf16x8*)(&ep[ch * 512 + lane * 8]);
      const size_t Rg = bm * 8 + wm * 4 + mt;
      const size_t cg = bn * 4 + wn * 2 + cc;
      *(bf16x8*)((u16*)E4out + (Rg * NCH + cg) * 512 + lane * 8) = v;
    }
  } else {
    #pragma unroll
    for (int mt = 0; mt < 4; ++mt) {
      #pragma unroll
      for (int r = 0; r < 4; ++r) {
        const int gm = bm * 128 + wm * 64 + mt * 16 + q * 4 + r;
        const float inv = 1.0f / rowsum[gm];
        #pragma unroll
        for (int nt = 0; nt < 4; ++nt) {
          const int gn = bn * 128 + wn * 64 + nt * 16 + lr;
          if (gn < NCLS) {
            float pt = acc[mt][nt][r] * inv;                 // p_tar_new
            float pv = p_vlm[(size_t)gm * NCLS + gn];
            // p_mix = (et*pt+ev*pv)/(et+ev) with rr=ev/et: one exp instead of two
            float lt = pt * __logf(pt + 1e-6f);
            float lv = pv * __logf(pv + 1e-6f);
            float rr = __expf(lv - lt);
            mix_out[(size_t)gm * NCLS + gn] = (pt + rr * pv) / (1.0f + rr);
          }
        }
      }
    }
  }
}

// ---- bank EMA update
__global__ __launch_bounds__(256)
void bank_update(const float* __restrict__ bank, const float* __restrict__ sums,
                 const float* __restrict__ counts, const float* __restrict__ alpha,
                 float* __restrict__ out) {
  const int idx = blockIdx.x * 256 + threadIdx.x;
  if (idx >= NCLS * NCLS) return;
  const int r = idx / NCLS;
  const float cnt = counts[r];
  const float bv  = bank[idx];
  const float a   = alpha[0];
  out[idx] = (cnt > 0.0f) ? a * bv + (1.0f - a) * (sums[idx] / cnt) : bv;
}

extern "C" void kernel_launch(void* const* d_in, const int* in_sizes, int n_in,
                              void* d_out, int out_size, void* d_ws, size_t ws_size,
                              hipStream_t stream) {
  const float* p_tar = (const float*)d_in[0];
  const float* p_vlm = (const float*)d_in[1];
  const float* alpha = (const float*)d_in[2];
  const float* bank  = (const float*)d_in[3];
  float* out_mix  = (float*)d_out;                         // [32768*1000]
  float* out_bank = (float*)d_out + (size_t)NROWS * NCLS;  // [1000*1000]

  char* w = (char*)d_ws;
  __hip_bfloat16* A4  = (__hip_bfloat16*)w; w += (size_t)NROWS * KP * 2;  // 64 MB
  __hip_bfloat16* E4  = (__hip_bfloat16*)w; w += (size_t)NROWS * KP * 2;  // 64 MB
  __hip_bfloat16* M4  = (__hip_bfloat16*)w; w += (size_t)KP * KP * 2;     // 2 MB
  __hip_bfloat16* MT4 = (__hip_bfloat16*)w; w += (size_t)KP * KP * 2;     // 2 MB
  float* sums   = (float*)w;                w += (size_t)NCLS * NCLS * 4; // 4 MB
  float* counts = (float*)w;                w += 1024 * 4;
  float* rs     = (float*)w;                w += (size_t)NROWS * 4;

  // zero atomic accumulators: sums + counts + rs are contiguous
  hipMemsetAsync(sums, 0, (size_t)NCLS * NCLS * 4 + 1024 * 4 + (size_t)NROWS * 4, stream);

  prep4_bank<<<dim3(32, 32), 128, 0, stream>>>(bank, M4, MT4);
  rows4_kernel<<<NROWS / 16, 256, 0, stream>>>(p_tar, p_vlm, A4, sums, counts);
  gemm4<1><<<2048, 256, 0, stream>>>(
      (const u16*)A4, (const u16*)M4, E4, rs, nullptr, nullptr);
  gemm4<2><<<2048, 256, 0, stream>>>(
      (const u16*)E4, (const u16*)MT4, nullptr, rs, p_vlm, out_mix);
  bank_update<<<(NCLS * NCLS + 255) / 256, 256, 0, stream>>>(bank, sums, counts, alpha, out_bank);
}

// Round 6
// 594.877 us; speedup vs baseline: 1.0922x; 1.0922x over previous
//
#include <hip/hip_runtime.h>
#include <hip/hip_bf16.h>
#include <cstdint>
#include <cstddef>

#define NROWS 32768
#define NCLS  1000
#define KP    1024   // padded class dim
#define NCH   32     // k-chunks per panel (KP/32)
#define NT    32     // K-tiles per GEMM (BK=32)

typedef unsigned short u16;
typedef __bf16 bf16x8 __attribute__((ext_vector_type(8)));
typedef float  f32x4  __attribute__((ext_vector_type(4)));

// Fragment-chunk layout ("X4"): matrix [Rows][KP] stored as
//   chunk(R, c) = 1KB block at ((R*NCH)+c)*512 halfwords, R = row/16, c = k/32
//   slot l (l=0..63, 16B) = elements [R*16 + (l&15)][c*32 + (l>>4)*8 + j], j=0..7
// => staging global loads, global_load_lds lane scatter, LDS fragment reads,
//    and MFMA A/B operand layout (m=lane&15, k=(lane>>4)*8+j) are ALL base+lane*16,
//    so LDS staging is linear and conflict-free (measured 0 all session).

__device__ __forceinline__ void gld_lds16(const u16* g, u16* l) {
  __builtin_amdgcn_global_load_lds(
      (const __attribute__((address_space(1))) unsigned int*)g,
      (__attribute__((address_space(3))) unsigned int*)l, 16, 0, 0);
}

// ---- prep: bank f32 [1000x1000] -> M4 and MT4 (fragment-chunk, zero-padded to 1024)
__global__ __launch_bounds__(128)
void prep4_bank(const float* __restrict__ bank,
                __hip_bfloat16* __restrict__ M4,
                __hip_bfloat16* __restrict__ MT4) {
  __shared__ float tile[32][33];
  const int tx = blockIdx.x;  // col chunk (k)
  const int ty = blockIdx.y;  // row chunk (j)
  const int t  = threadIdx.x;
  {
    const int r = t >> 2, c0 = (t & 3) * 8;
    const int gj = ty * 32 + r;
    #pragma unroll
    for (int j = 0; j < 8; ++j) {
      const int gk = tx * 32 + c0 + j;
      tile[r][c0 + j] = (gj < NCLS && gk < NCLS) ? bank[gj * NCLS + gk] : 0.0f;
    }
  }
  __syncthreads();
  const int w = t >> 6, lane = t & 63, lr = lane & 15, qq = lane >> 4;
  if (w == 0) {
    #pragma unroll
    for (int s = 0; s < 2; ++s) {
      bf16x8 o;
      #pragma unroll
      for (int j = 0; j < 8; ++j) o[j] = (__bf16)tile[s * 16 + lr][qq * 8 + j];
      *(bf16x8*)((u16*)M4 + ((size_t)(ty * 2 + s) * NCH + tx) * 512 + lane * 8) = o;
    }
  } else {
    #pragma unroll
    for (int s = 0; s < 2; ++s) {
      bf16x8 o;
      #pragma unroll
      for (int j = 0; j < 8; ++j) o[j] = (__bf16)tile[qq * 8 + j][s * 16 + lr];
      *(bf16x8*)((u16*)MT4 + ((size_t)(tx * 2 + s) * NCH + ty) * 512 + lane * 8) = o;
    }
  }
}

// ---- fused: p_tar -> A4 (fragment-chunk bf16), argmax agreement + segment-sum atomics
// One 16-row panel per BLOCK; the 4 waves k-split the 32 chunks (8 each).
// Partial argmax per wave combined through LDS; first-occurrence ties preserved.
__global__ __launch_bounds__(256)
void rows4_kernel(const float* __restrict__ p_tar, const float* __restrict__ p_vlm,
                  __hip_bfloat16* __restrict__ A4,
                  float* __restrict__ sums, float* __restrict__ counts) {
  __shared__ float sT[4][16]; __shared__ int siT[4][16];
  __shared__ float sV[4][16]; __shared__ int siV[4][16];
  const int w = threadIdx.x >> 6, lane = threadIdx.x & 63;
  const int lr = lane & 15, q = lane >> 4;
  const int panel = blockIdx.x;                  // 0..2047
  const int row   = panel * 16 + lr;
  const float* tr = p_tar + (size_t)row * NCLS;
  const float* vr = p_vlm + (size_t)row * NCLS;
  u16* a4 = (u16*)A4 + (size_t)panel * NCH * 512 + lane * 8;

  float bvT = -1.0f; int biT = 0;
  float bvV = -1.0f; int biV = 0;
  for (int c = w * 8; c < w * 8 + 8; ++c) {
    const int k0 = c * 32 + q * 8;
    float v[8];
    if (k0 < NCLS) {
      float4 x = *(const float4*)(tr + k0);
      float4 y = *(const float4*)(tr + k0 + 4);
      v[0] = x.x; v[1] = x.y; v[2] = x.z; v[3] = x.w;
      v[4] = y.x; v[5] = y.y; v[6] = y.z; v[7] = y.w;
    } else {
      #pragma unroll
      for (int j = 0; j < 8; ++j) v[j] = 0.0f;
    }
    bf16x8 o;
    #pragma unroll
    for (int j = 0; j < 8; ++j) {
      o[j] = (__bf16)v[j];
      if (v[j] > bvT) { bvT = v[j]; biT = k0 + j; }
    }
    *(bf16x8*)(a4 + (size_t)c * 512) = o;
    if (k0 < NCLS) {
      float4 x = *(const float4*)(vr + k0);
      float4 y = *(const float4*)(vr + k0 + 4);
      float u[8] = {x.x, x.y, x.z, x.w, y.x, y.y, y.z, y.w};
      #pragma unroll
      for (int j = 0; j < 8; ++j)
        if (u[j] > bvV) { bvV = u[j]; biV = k0 + j; }
    }
  }
  #pragma unroll
  for (int d = 16; d < 64; d <<= 1) {
    float ov = __shfl_xor(bvT, d); int oi = __shfl_xor(biT, d);
    if (ov > bvT || (ov == bvT && oi < biT)) { bvT = ov; biT = oi; }
    float ov2 = __shfl_xor(bvV, d); int oi2 = __shfl_xor(biV, d);
    if (ov2 > bvV || (ov2 == bvV && oi2 < biV)) { bvV = ov2; biV = oi2; }
  }
  if (q == 0) { sT[w][lr] = bvT; siT[w][lr] = biT; sV[w][lr] = bvV; siV[w][lr] = biV; }
  __syncthreads();
  float cT = sT[0][lr]; int ciT = siT[0][lr];
  float cV = sV[0][lr]; int ciV = siV[0][lr];
  #pragma unroll
  for (int ww = 1; ww < 4; ++ww) {
    float v1 = sT[ww][lr]; if (v1 > cT) { cT = v1; ciT = siT[ww][lr]; }
    float v2 = sV[ww][lr]; if (v2 > cV) { cV = v2; ciV = siV[ww][lr]; }
  }
  if (w == 0) {                                  // rare (~B/NCLS rows agree)
    const int ag = (ciT == ciV) ? 1 : 0;
    for (int rr = 0; rr < 16; ++rr) {
      const int agr = __shfl(ag, rr);
      if (agr) {                                 // wave-uniform
        const int cls = __shfl(ciT, rr);
        const float* trr = p_tar + (size_t)(panel * 16 + rr) * NCLS;
        for (int k = lane; k < NCLS; k += 64)
          atomicAdd(&sums[(size_t)cls * NCLS + k], trr[k]);
        if (lane == 0) atomicAdd(&counts[cls], 1.0f);
      }
    }
  }
}

// ---- 256x256 8-wave phase-split MFMA GEMM (8-phase-template port, T3+T4+T5).
// 8 waves (2 wr x 4 wc); per-wave output 128x64 = acc[8][4] f32x4.
// LDS 64KB: A dbuf [2][16 panels][1KB] @0, B dbuf @32KB. Per K-tile t:
//   top:   stage A(t+1) [2 gld_lds], s_waitcnt vmcnt(2) (counted, never 0
//          until the peeled last tile), s_barrier -> slot s valid.
//   ph0:   ds_read af[0..3]+bfr[0..3] | stage B(t+1) | barrier |
//          setprio(1) 16 MFMA setprio(0) | barrier
//   ph1:   ds_read af[4..7] | barrier | setprio(1) 16 MFMA setprio(0)
// Per-wave vmcnt FIFO: [A(t) 2, B(t) 2, A(t+1) 2] -> vmcnt(2) == A(t),B(t)
// landed, A(t+1) in flight. Landing slack >= 2 phases (~1000 cyc) covers
// L2/L3/HBM. Swizzle: xcd=L&7, bn fastest -> 4 bn-sharers of each 512KB
// A-stripe are consecutive same-XCD dispatches; B (2MB) XCD-L2-resident.
// WHICH==1: E4 = frag-chunk bf16 exp(norm*S) (cols>=1000 -> 0) + atomic rowsum
// WHICH==2: p_mix row-major f32
template <int WHICH>
__global__ __launch_bounds__(512, 2)
void gemm8(const u16* __restrict__ A4, const u16* __restrict__ B4,
           __hip_bfloat16* __restrict__ E4out, float* __restrict__ rowsum,
           const float* __restrict__ p_vlm, float* __restrict__ mix_out) {
  __shared__ u16 SH[32768];   // 64KB
  const int tid  = threadIdx.x;
  const int w    = tid >> 6;
  const int lane = tid & 63;
  const int lr   = lane & 15;
  const int q    = lane >> 4;
  const int wr   = w >> 2;                        // 0..1 (row half)
  const int wc   = w & 3;                         // 0..3 (col quarter)
  const int L    = blockIdx.x;                    // 0..511
  const int xcd  = L & 7;
  const int j    = L >> 3;                        // 0..63 within-XCD order
  const int bm   = xcd * 16 + (j >> 2);           // 0..127; 4 consecutive j share bm
  const int bn   = j & 3;                         // 0..3 fastest within XCD

  f32x4 acc[8][4] = {};

  // wave w stages A panels {w, w+8} and B panels {w, w+8} of the 16-panel tiles
  const u16* gA0 = A4 + ((size_t)(bm * 16 + w)     * NCH) * 512 + lane * 8;
  const u16* gA1 = A4 + ((size_t)(bm * 16 + w + 8) * NCH) * 512 + lane * 8;
  const u16* gB0 = B4 + ((size_t)(bn * 16 + w)     * NCH) * 512 + lane * 8;
  const u16* gB1 = B4 + ((size_t)(bn * 16 + w + 8) * NCH) * 512 + lane * 8;

  #define STAGE_A(t, s)                                         \
    do { const size_t ko = (size_t)(t) * 512;                   \
      gld_lds16(gA0 + ko, SH + (s) * 8192 + w * 512);           \
      gld_lds16(gA1 + ko, SH + (s) * 8192 + (w + 8) * 512);     \
    } while (0)
  #define STAGE_B(t, s)                                         \
    do { const size_t ko = (size_t)(t) * 512;                   \
      gld_lds16(gB0 + ko, SH + 16384 + (s) * 8192 + w * 512);   \
      gld_lds16(gB1 + ko, SH + 16384 + (s) * 8192 + (w + 8) * 512); \
    } while (0)

  STAGE_A(0, 0);
  STAGE_B(0, 0);

  for (int t = 0; t < NT; ++t) {
    const int s = t & 1, ns = s ^ 1;
    if (t + 1 < NT) {
      STAGE_A(t + 1, ns);
      asm volatile("s_waitcnt vmcnt(2)" ::: "memory");  // A(t),B(t) landed
    } else {
      asm volatile("s_waitcnt vmcnt(0)" ::: "memory");  // peeled tail drain
    }
    __builtin_amdgcn_s_barrier();
    asm volatile("" ::: "memory");
    const u16* sA = SH + s * 8192;
    const u16* sB = SH + 16384 + s * 8192;
    // phase 0: reads + B-stage, then MFMA quadrant mt 0..3
    bf16x8 af[4], bfr[4];
    #pragma unroll
    for (int nt = 0; nt < 4; ++nt)
      bfr[nt] = *(const bf16x8*)(sB + (wc * 4 + nt) * 512 + lane * 8);
    #pragma unroll
    for (int mt = 0; mt < 4; ++mt)
      af[mt] = *(const bf16x8*)(sA + (wr * 8 + mt) * 512 + lane * 8);
    if (t + 1 < NT) STAGE_B(t + 1, ns);
    asm volatile("" ::: "memory");
    __builtin_amdgcn_s_barrier();
    asm volatile("" ::: "memory");
    __builtin_amdgcn_s_setprio(1);
    #pragma unroll
    for (int mt = 0; mt < 4; ++mt)
      #pragma unroll
      for (int nt = 0; nt < 4; ++nt)
        acc[mt][nt] = __builtin_amdgcn_mfma_f32_16x16x32_bf16(af[mt], bfr[nt], acc[mt][nt], 0, 0, 0);
    __builtin_amdgcn_s_setprio(0);
    asm volatile("" ::: "memory");
    __builtin_amdgcn_s_barrier();
    asm volatile("" ::: "memory");
    // phase 1: reads + MFMA quadrant mt 4..7 (bfr reused)
    bf16x8 af2[4];
    #pragma unroll
    for (int mt = 0; mt < 4; ++mt)
      af2[mt] = *(const bf16x8*)(sA + (wr * 8 + 4 + mt) * 512 + lane * 8);
    asm volatile("" ::: "memory");
    __builtin_amdgcn_s_barrier();
    asm volatile("" ::: "memory");
    __builtin_amdgcn_s_setprio(1);
    #pragma unroll
    for (int mt = 0; mt < 4; ++mt)
      #pragma unroll
      for (int nt = 0; nt < 4; ++nt)
        acc[4 + mt][nt] = __builtin_amdgcn_mfma_f32_16x16x32_bf16(af2[mt], bfr[nt], acc[4 + mt][nt], 0, 0, 0);
    __builtin_amdgcn_s_setprio(0);
    // no trailing barrier: next iter's vmcnt+barrier orders slot reuse
  }
  #undef STAGE_A
  #undef STAGE_B

  __syncthreads();                 // K-loop LDS reads done; reuse as bounce
  const float NORM = 0.03162277660168379f;  // 1/sqrt(1000)
  if (WHICH == 1) {
    u16* ep = SH + w * 4096;       // 8KB per-wave private region
    #pragma unroll
    for (int rr2 = 0; rr2 < 2; ++rr2) {          // two 4-mt rounds (LDS budget)
      #pragma unroll
      for (int mtl = 0; mtl < 4; ++mtl) {
        const int mt = rr2 * 4 + mtl;
        float psum[4] = {0.f, 0.f, 0.f, 0.f};
        #pragma unroll
        for (int nt = 0; nt < 4; ++nt) {
          const int gn = bn * 256 + wc * 64 + nt * 16 + lr;
          const int cc = nt >> 1;
          const int q2 = (nt & 1) * 2 + (lr >> 3);
          const int jj2 = lr & 7;
          #pragma unroll
          for (int r = 0; r < 4; ++r) {
            float e = (gn < NCLS) ? __expf(acc[mt][nt][r] * NORM) : 0.0f;
            psum[r] += e;
            __hip_bfloat16 h = __float2bfloat16(e);
            ep[(mtl * 2 + cc) * 512 + (q2 * 16 + q * 4 + r) * 8 + jj2] = *(u16*)&h;
          }
        }
        #pragma unroll
        for (int r = 0; r < 4; ++r) {
          float sm = psum[r];
          sm += __shfl_xor(sm, 1); sm += __shfl_xor(sm, 2);
          sm += __shfl_xor(sm, 4); sm += __shfl_xor(sm, 8);
          if (lr == 0)
            atomicAdd(&rowsum[bm * 256 + wr * 128 + mt * 16 + q * 4 + r], sm);
        }
      }
      #pragma unroll
      for (int ch = 0; ch < 8; ++ch) {   // coalesced 1KB flushes
        const int mtl = ch >> 1, cc = ch & 1;
        bf16x8 v = *(const bf16x8*)(ep + ch * 512 + lane * 8);
        const size_t Rg = bm * 16 + wr * 8 + rr2 * 4 + mtl;
        const size_t cg = bn * 8 + wc * 2 + cc;
        *(bf16x8*)((u16*)E4out + (Rg * NCH + cg) * 512 + lane * 8) = v;
      }
    }
  } else {
    #pragma unroll
    for (int mt = 0; mt < 8; ++mt) {
      #pragma unroll
      for (int r = 0; r < 4; ++r) {
        const int gm = bm * 256 + wr * 128 + mt * 16 + q * 4 + r;
        const float inv = 1.0f / rowsum[gm];
        #pragma unroll
        for (int nt = 0; nt < 4; ++nt) {
          const int gn = bn * 256 + wc * 64 + nt * 16 + lr;
          if (gn < NCLS) {
            float pt = acc[mt][nt][r] * inv;                 // p_tar_new
            float pv = p_vlm[(size_t)gm * NCLS + gn];
            // p_mix = (et*pt+ev*pv)/(et+ev) with rr=ev/et: one exp
            float lt = pt * __logf(pt + 1e-6f);
            float lv = pv * __logf(pv + 1e-6f);
            float rr = __expf(lv - lt);
            mix_out[(size_t)gm * NCLS + gn] = (pt + rr * pv) / (1.0f + rr);
          }
        }
      }
    }
  }
}

// ---- bank EMA update
__global__ __launch_bounds__(256)
void bank_update(const float* __restrict__ bank, const float* __restrict__ sums,
                 const float* __restrict__ counts, const float* __restrict__ alpha,
                 float* __restrict__ out) {
  const int idx = blockIdx.x * 256 + threadIdx.x;
  if (idx >= NCLS * NCLS) return;
  const int r = idx / NCLS;
  const float cnt = counts[r];
  const float bv  = bank[idx];
  const float a   = alpha[0];
  out[idx] = (cnt > 0.0f) ? a * bv + (1.0f - a) * (sums[idx] / cnt) : bv;
}

extern "C" void kernel_launch(void* const* d_in, const int* in_sizes, int n_in,
                              void* d_out, int out_size, void* d_ws, size_t ws_size,
                              hipStream_t stream) {
  const float* p_tar = (const float*)d_in[0];
  const float* p_vlm = (const float*)d_in[1];
  const float* alpha = (const float*)d_in[2];
  const float* bank  = (const float*)d_in[3];
  float* out_mix  = (float*)d_out;                         // [32768*1000]
  float* out_bank = (float*)d_out + (size_t)NROWS * NCLS;  // [1000*1000]

  char* w = (char*)d_ws;
  __hip_bfloat16* A4  = (__hip_bfloat16*)w; w += (size_t)NROWS * KP * 2;  // 64 MB
  __hip_bfloat16* E4  = (__hip_bfloat16*)w; w += (size_t)NROWS * KP * 2;  // 64 MB
  __hip_bfloat16* M4  = (__hip_bfloat16*)w; w += (size_t)KP * KP * 2;     // 2 MB
  __hip_bfloat16* MT4 = (__hip_bfloat16*)w; w += (size_t)KP * KP * 2;     // 2 MB
  float* sums   = (float*)w;                w += (size_t)NCLS * NCLS * 4; // 4 MB
  float* counts = (float*)w;                w += 1024 * 4;
  float* rs     = (float*)w;                w += (size_t)NROWS * 4;

  // zero atomic accumulators: sums + counts + rs are contiguous
  hipMemsetAsync(sums, 0, (size_t)NCLS * NCLS * 4 + 1024 * 4 + (size_t)NROWS * 4, stream);

  prep4_bank<<<dim3(32, 32), 128, 0, stream>>>(bank, M4, MT4);
  rows4_kernel<<<NROWS / 16, 256, 0, stream>>>(p_tar, p_vlm, A4, sums, counts);
  gemm8<1><<<512, 512, 0, stream>>>(
      (const u16*)A4, (const u16*)M4, E4, rs, nullptr, nullptr);
  gemm8<2><<<512, 512, 0, stream>>>(
      (const u16*)E4, (const u16*)MT4, nullptr, rs, p_vlm, out_mix);
  bank_update<<<(NCLS * NCLS + 255) / 256, 256, 0, stream>>>(bank, sums, counts, alpha, out_bank);
}